// Round 2
// baseline (80.597 us; speedup 1.0000x reference)
//
#include <hip/hip_runtime.h>
#include <hip/hip_bf16.h>

typedef __attribute__((ext_vector_type(8))) short short8;   // 8 bf16 (4 VGPRs)
typedef __attribute__((ext_vector_type(4))) float f32x4;
typedef unsigned int uint;
typedef __attribute__((ext_vector_type(4))) uint uint4v;    // align 16 -> dwordx4/b128

#define AS1 __attribute__((address_space(1)))
#define AS3 __attribute__((address_space(3)))

// ws: Rp4 [0,1MB) | Qp4 [1MB,1.25MB) | xph [1.25MB, +34.1MB)
#define QB_OFF  (1u << 20)
#define XPH_OFF (1310720u)
// xph byte addr: n*1115136 + row*16896 + col*256 + c*2   (row,col in 0..65, c in 0..127)
// Rp4: [s 0..63][p 0..1023]*16B ; at (s,p): col=p>>2, wu=p&3, holds R[col][k=s*32+wu*8+e]
//      (k-order: g=k>>7 window, c=k&127; f=c*16+g)
// Qp4: [ks 0..7][p 0..2047]*16B ; at (ks,p): col=p>>2, unit=p&3, Q[col][ks*32+unit*8+e]

__device__ __forceinline__ uint bf16r(float f) {
    uint u = __float_as_uint(f);
    u += 0x7FFFu + ((u >> 16) & 1u);
    return u >> 16;
}
__device__ __forceinline__ uint pk2(float lo, float hi) {
    return bf16r(lo) | (bf16r(hi) << 16);
}

// ---------------- prep: NHWC-padded bf16 x, sub-slab R, K-slab Q ----------------
__global__ __launch_bounds__(256) void prep_kernel(
    const float* __restrict__ x, const float* __restrict__ Q, const float* __restrict__ R,
    char* __restrict__ Rp4, char* __restrict__ Qp4, char* __restrict__ xph)
{
    const int bid = blockIdx.x, tid = threadIdx.x;
    if (bid < 2048) {                       // transpose: n = bid>>6, h = bid&63
        __shared__ float xt[128 * 65];
        const int n = bid >> 6, h = bid & 63;
        {   // read x[n][c][h][w] coalesced, stage to LDS
            const int c = tid >> 1, half = tid & 1;
            const float4* src = (const float4*)(x + (((size_t)(n * 128 + c) * 64 + h) * 64 + half * 32));
            #pragma unroll
            for (int q = 0; q < 8; ++q) {
                float4 v = src[q];
                float* d = &xt[c * 65 + half * 32 + q * 4];
                d[0] = v.x; d[1] = v.y; d[2] = v.z; d[3] = v.w;
            }
        }
        __syncthreads();
        {   // write xph[n][h+1][w+1][c] (32 channels per thread)
            const int w = tid >> 2, cq = tid & 3;
            uint pw[16];
            #pragma unroll
            for (int m = 0; m < 16; ++m)
                pw[m] = pk2(xt[(cq * 32 + 2 * m) * 65 + w], xt[(cq * 32 + 2 * m + 1) * 65 + w]);
            char* dst = xph + (size_t)n * 1115136 + (size_t)(h + 1) * 16896 + (w + 1) * 256 + cq * 64;
            #pragma unroll
            for (int i = 0; i < 4; ++i) {
                uint4v q4 = { pw[4 * i], pw[4 * i + 1], pw[4 * i + 2], pw[4 * i + 3] };
                *(uint4v*)(dst + i * 16) = q4;
            }
        }
        if (tid < 32) {                      // col borders 0 and 65
            int side = tid >> 4, e = tid & 15;
            uint4v z = {0, 0, 0, 0};
            *(uint4v*)(xph + (size_t)n * 1115136 + (size_t)(h + 1) * 16896 + side * 65 * 256 + e * 16) = z;
        }
        if (h == 0) {                        // row borders 0 and 65
            uint4v z = {0, 0, 0, 0};
            #pragma unroll
            for (int it = 0; it < 9; ++it) {
                int idx = tid + it * 256;
                if (idx < 2112) {
                    int rr = (idx >= 1056) ? 65 : 0;
                    int jj = idx - (rr ? 1056 : 0);
                    int col = jj >> 4, e = jj & 15;
                    *(uint4v*)(xph + (size_t)n * 1115136 + (size_t)rr * 16896 + col * 256 + e * 16) = z;
                }
            }
        }
    } else if (bid < 2304) {                // R -> Rp4[s][p]  (16KB sub-slab per K=32 chunk)
        int g = (bid - 2048) * 256 + tid;   // 0..65535
        int s = g >> 10, p = g & 1023;
        int col = p >> 2, wu = p & 3;
        // k = s*32 + wu*8 + e ; g_win = s>>2 ; c = (s&3)*32 + wu*8 + e ; f = c*16 + g_win
        const float* src = R + (size_t)col * 2048 + (((s & 3) * 32 + wu * 8) * 16 + (s >> 2));
        uint pw[4];
        #pragma unroll
        for (int m = 0; m < 4; ++m)
            pw[m] = pk2(src[(2 * m) * 16], src[(2 * m + 1) * 16]);
        uint4v q4 = { pw[0], pw[1], pw[2], pw[3] };
        *(uint4v*)(Rp4 + (size_t)s * 16384 + p * 16) = q4;
    } else {                                 // Q -> Qp4[ks][p] (linear 64B-col-stride)
        int g = (bid - 2304) * 256 + tid;   // 0..16383
        int ks = g >> 11, p = g & 2047;
        int col = p >> 2, unit = p & 3;
        const float4* s = (const float4*)(Q + (size_t)col * 256 + ks * 32 + unit * 8);
        float4 a = s[0], b = s[1];
        uint4v q4 = { pk2(a.x, a.y), pk2(a.z, a.w), pk2(b.x, b.y), pk2(b.z, b.w) };
        *(uint4v*)(Qp4 + (size_t)ks * 32768 + p * 16) = q4;
    }
}

// ---------------- fused: BM=128 x BN=256, 512 thr / 8 waves, 1 block/CU ----------------
// 64 sub-phases (one K=32 chunk each), DEPTH-4 rotation, counted vmcnt (never 0 in loop):
//   LDS: X 4x8KB [0,32K) | B 4x16KB [32K,98K) | QA 32KB [98K,131K) | QB [64K,98K) (ex-B23)
//        ttile 64KB [0,64K) after gemm1 | ep f32 at 0 after gemm2
// Batch at s = {B(s+3):2 loads, X(s+3):1 load}; barrier end of s needs batch(s+1) drained
// (issued at s-2) -> vmcnt(6) keeps batches s+2,s+3 in flight. DMA window = 3 bodies.
__global__ __launch_bounds__(512, 2) void fused_kernel(
    const char* __restrict__ xph, const char* __restrict__ Rp4,
    const char* __restrict__ Qp4, float* __restrict__ out)
{
    extern __shared__ __align__(16) char lds[];

    const int blk = blockIdx.x;
    const int b = (blk & 7) * 32 + (blk >> 3);  // XCD-contiguous swizzle (256%8==0)
    const int n = b >> 3, vt = b & 7;           // vt: 4 output-row block
    const int tid = threadIdx.x;
    const int wave = tid >> 6, lane = tid & 63;
    const int lr = lane & 15, kg = lane >> 4;
    const int lr7 = lr & 7;
    const int wm = wave >> 2, wn = wave & 3;    // gemm1: rows wm*64.., cols wn*64..

    const char* xbase = xph + (size_t)n * 1115136;
    const int u16 = tid * 16;

    // X DMA per-thread constant: unit u=tid -> pos m=u>>2 (rh=m>>5, cl=m&31), c-unit cu=u&3
    const int xm = tid >> 2, xcu = tid & 3;
    const int xc = (8 * vt + 2 * (xm >> 5)) * 16896 + (2 * (xm & 31)) * 256 + xcu * 16;

    // gemm1 fragment read bases (64B/row|col layout; kg*16 spreads bank residues -> no xor)
    const int a0 = wm * 4096 + lr * 64 + kg * 16;
    const int bb0 = wn * 4096 + lr * 64 + kg * 16;

    // gemm2: ttile row bases + row swizzle, Q col bases
    int tb[4];
    #pragma unroll
    for (int mf = 0; mf < 4; ++mf) tb[mf] = (wm * 64 + mf * 16 + lr) * 512;
    const int tswz = (lr7 << 4) ^ ((lr & 8) << 2);
    int qbase[8];
    #pragma unroll
    for (int nf = 0; nf < 8; ++nf)
        qbase[nf] = ((wn >> 1) * 256 + (nf >> 2) * 128 + (wn & 1) * 64 + (nf & 3) * 16 + lr) * 64 + kg * 16;

#define BDMA2(s_) { _Pragma("unroll") for (int q = 0; q < 2; ++q)                       \
        __builtin_amdgcn_global_load_lds(                                               \
            (const AS1 void*)(Rp4 + (size_t)(s_) * 16384 + q * 8192 + u16),             \
            (AS3 void*)(lds + 32768 + ((s_) & 3) * 16384 + q * 8192 + u16), 16, 0, 0); }
#define XDMA1(s_) __builtin_amdgcn_global_load_lds(                                     \
        (const AS1 void*)(xbase + xc + ((s_) >> 4) * 16896 + (((s_) >> 2) & 3) * 256 + ((s_) & 3) * 64), \
        (AS3 void*)(lds + ((s_) & 3) * 8192 + u16), 16, 0, 0);
#define QDMA(ks_) { _Pragma("unroll") for (int q = 0; q < 4; ++q)                       \
        __builtin_amdgcn_global_load_lds(                                               \
            (const AS1 void*)(Qp4 + (size_t)(ks_) * 32768 + q * 8192 + u16),            \
            (AS3 void*)(lds + (((ks_) & 1) ? 65536 : 98304) + q * 8192 + u16), 16, 0, 0); }

#define BAR(Nstr) { __builtin_amdgcn_sched_barrier(0);                                  \
        asm volatile("s_waitcnt vmcnt(" Nstr ") lgkmcnt(0)\n\ts_barrier" ::: "memory"); \
        __builtin_amdgcn_sched_barrier(0); }
#define LBAR { __builtin_amdgcn_sched_barrier(0);                                       \
        asm volatile("s_waitcnt lgkmcnt(0)\n\ts_barrier" ::: "memory");                 \
        __builtin_amdgcn_sched_barrier(0); }

    f32x4 acc[4][4];
    #pragma unroll
    for (int i = 0; i < 4; ++i)
        #pragma unroll
        for (int j = 0; j < 4; ++j) acc[i][j] = (f32x4)0.f;

    // prologue: batches 0,1,2 in flight; drain batch 0 (keep 1,2 -> vmcnt(6))
    BDMA2(0) XDMA1(0) BDMA2(1) XDMA1(1) BDMA2(2) XDMA1(2)
    BAR("6")

    // ---- gemm1: 64 sub-phases, 16 MFMA each ----
    #pragma unroll
    for (int s = 0; s < 64; ++s) {
        if (s <= 60) { BDMA2(s + 3) XDMA1(s + 3) }
        if (s == 60) QDMA(0)                 // QA region [98304,131072) always free
        const char* xs = lds + (s & 3) * 8192;
        const char* bs = lds + 32768 + (s & 3) * 16384;
        short8 af[4], bf[4];
        #pragma unroll
        for (int mf = 0; mf < 4; ++mf)
            af[mf] = *(const short8*)(xs + a0 + mf * 1024);
        #pragma unroll
        for (int nf = 0; nf < 4; ++nf)
            bf[nf] = *(const short8*)(bs + bb0 + nf * 1024);
        #pragma unroll
        for (int nf = 0; nf < 4; ++nf)
            #pragma unroll
            for (int mf = 0; mf < 4; ++mf)
                acc[mf][nf] = __builtin_amdgcn_mfma_f32_16x16x32_bf16(af[mf], bf[nf], acc[mf][nf], 0, 0, 0);
        // ledger: need batch(s+1) drained; newer = batches s+2,s+3 (3 loads each) + Q0 tail
        if (s <= 59)      { BAR("6") }
        else if (s == 60) { BAR("10") }      // b62(3)+b63(3)+Q0(4)
        else if (s == 61) { BAR("7") }       // b63(3)+Q0(4)
        else              { BAR("4") }       // s=62: Q0 ; s=63: keep Q0 in flight
    }

    // ---- ttile: acc -> bf16 [128 rows][512B] at lds+0 (X + B01 regions dead) ----
    QDMA(1)                                  // QB = ex-B slabs 2,3 (dead after s=63 barrier)
    #pragma unroll
    for (int mf = 0; mf < 4; ++mf)
        #pragma unroll
        for (int nf = 0; nf < 4; ++nf)
            #pragma unroll
            for (int r = 0; r < 4; ++r) {
                int row = wm * 64 + mf * 16 + kg * 4 + r;
                int col = wn * 64 + nf * 16 + lr;
                *(ushort*)(lds + row * 512 +
                           ((col * 2) ^ ((row & 7) << 4) ^ ((row & 8) << 2))) =
                    (ushort)bf16r(acc[mf][nf][r]);
            }
    BAR("4")                                 // drain Q0 (keep Q1); lgkm orders ttile

    // ---- gemm2: Y[128][512] = ttile @ Q^T ; Q dbuf QA/QB ----
    f32x4 acc2[4][8];
    #pragma unroll
    for (int i = 0; i < 4; ++i)
        #pragma unroll
        for (int j = 0; j < 8; ++j) acc2[i][j] = (f32x4)0.f;
    #pragma unroll
    for (int ks = 0; ks < 8; ++ks) {
        if (ks >= 1 && ks <= 6) QDMA(ks + 1)
        const char* qs = lds + ((ks & 1) ? 65536 : 98304);
        short8 af2[4];
        #pragma unroll
        for (int mf = 0; mf < 4; ++mf)
            af2[mf] = *(const short8*)(lds + tb[mf] + ((ks * 64 + kg * 16) ^ tswz));
        #pragma unroll
        for (int nf = 0; nf < 8; ++nf) {
            const short8 bq = *(const short8*)(qs + qbase[nf]);
            #pragma unroll
            for (int mf = 0; mf < 4; ++mf)
                acc2[mf][nf] = __builtin_amdgcn_mfma_f32_16x16x32_bf16(af2[mf], bq, acc2[mf][nf], 0, 0, 0);
        }
        if (ks <= 6) { BAR("0") }            // Q(ks+1) window = full ks body (Q is L2-hot)
    }

    // ---- epilogue: 4 passes (mh = local r_ov); lane holds 8 w-contiguous f32 -> b128 LDS
    const int si = wn >> 1, ochalf = wn & 1;
    #pragma unroll
    for (int mh = 0; mh < 4; ++mh) {
        LBAR
        if (wm == (mh >> 1)) {
            #pragma unroll
            for (int mfh = 0; mfh < 2; ++mfh) {
                const int mf = (mh & 1) * 2 + mfh;
                #pragma unroll
                for (int q = 0; q < 4; ++q) {
                    const int oc = ochalf * 64 + q * 16 + lr;
                    const int ub = si * 34816 + oc * 272 + (((4 * mfh + kg) ^ (oc & 7)) << 5);
                    // w = 32*mfh + 8*kg + 2*reg + sj ; sj=0 -> nf=q, sj=1 -> nf=4+q
                    f32x4 v0 = { acc2[mf][q][0], acc2[mf][4 + q][0], acc2[mf][q][1], acc2[mf][4 + q][1] };
                    f32x4 v1 = { acc2[mf][q][2], acc2[mf][4 + q][2], acc2[mf][q][3], acc2[mf][4 + q][3] };
                    *(f32x4*)(lds + ub) = v0;
                    *(f32x4*)(lds + ub + 16) = v1;
                }
            }
        }
        LBAR
        #pragma unroll
        for (int it = 0; it < 8; ++it) {
            int uidx = it * 512 + tid;
            int w4 = uidx & 15, oc = (uidx >> 4) & 127, sie = uidx >> 11;
            f32x4 v = *(const f32x4*)(lds + sie * 34816 + oc * 272 + ((w4 ^ (2 * (oc & 7))) << 4));
            *(f32x4*)(out + (size_t)n * 524288 + (size_t)oc * 4096
                          + (8 * vt + 2 * mh + sie) * 64 + w4 * 4) = v;
        }
    }
}

extern "C" void kernel_launch(void* const* d_in, const int* in_sizes, int n_in,
                              void* d_out, int out_size, void* d_ws, size_t ws_size,
                              hipStream_t stream) {
    const float* x = (const float*)d_in[0];
    const float* Q = (const float*)d_in[1];
    const float* R = (const float*)d_in[2];
    float* out = (float*)d_out;

    char* ws = (char*)d_ws;
    char* Rp4 = ws;
    char* Qp4 = ws + QB_OFF;
    char* xph = ws + XPH_OFF;

    prep_kernel<<<2368, 256, 0, stream>>>(x, Q, R, Rp4, Qp4, xph);
    fused_kernel<<<256, 512, 131072, stream>>>(xph, Rp4, Qp4, out);
}